// Round 7
// baseline (297.680 us; speedup 1.0000x reference)
//
#include <hip/hip_runtime.h>
#include <cstdint>
#include <cstddef>

#define F_IN 512
#define F_HID 32
#define N_CLS 16
#define BSH 7                 // 128 nodes per bucket
#define BNODES (1 << BSH)

#define GLDS16(gp, lp) __builtin_amdgcn_global_load_lds( \
    (const __attribute__((address_space(1))) void*)(gp), \
    (__attribute__((address_space(3))) void*)(lp), 16, 0, 0)

__device__ __forceinline__ float4 shfl_xor_f4(float4 v, int mask) {
    v.x = __shfl_xor(v.x, mask, 64);
    v.y = __shfl_xor(v.y, mask, 64);
    v.z = __shfl_xor(v.z, mask, 64);
    v.w = __shfl_xor(v.w, mask, 64);
    return v;
}

// ---------------- edge dtype detection (int32 vs int64) + bcnt zero ----------------
__global__ __launch_bounds__(256) void k_detect(const int* e, int* flag, int* bcnt) {
    __shared__ int zc;
    int t = threadIdx.x;
    if (t == 0) zc = 0;
    __syncthreads();
    int z = 0;
#pragma unroll
    for (int j = 0; j < 4; ++j)
        if (e[2 * (t * 4 + j) + 1] == 0) z++;
    if (z) atomicAdd(&zc, z);
    for (int i = t; i < 800; i += 256) bcnt[i] = 0;
    __syncthreads();
    if (t == 0) *flag = (zc >= 1016) ? 1 : 0;
}

__device__ __forceinline__ int edge_get(const void* e, int is64, long long idx) {
    return is64 ? (int)((const long long*)e)[idx] : ((const int*)e)[idx];
}

// ---------------- bucket histogram (LDS-aggregated) ----------------
__global__ __launch_bounds__(256) void k_bcount(const void* edges, const int* flag,
                                                int* bcnt, int E, int nbuk) {
    __shared__ int h[784];
    int t = threadIdx.x;
    for (int i = t; i < 784; i += 256) h[i] = 0;
    __syncthreads();
    int is64 = *flag;
    long long i = (long long)blockIdx.x * blockDim.x + t;
    long long step = (long long)gridDim.x * blockDim.x;
    for (; i < E; i += step) {
        int d = edge_get(edges, is64, (long long)E + i);
        atomicAdd(&h[d >> BSH], 1);
    }
    __syncthreads();
    for (int i2 = t; i2 < nbuk; i2 += 256)
        if (h[i2]) atomicAdd(&bcnt[i2], h[i2]);
}

// ---------------- bucket base scan (1 block, 1024 thr, nbuk<=1024) ----------------
__global__ __launch_bounds__(1024) void k_bscan(const int* bcnt, int* bbase, int* bcur,
                                                int nbuk, int E) {
    __shared__ int wsum[16];
    int t = threadIdx.x, lane = t & 63, w = t >> 6;
    int v = (t < nbuk) ? bcnt[t] : 0;
    int inc = v;
#pragma unroll
    for (int off = 1; off < 64; off <<= 1) {
        int u = __shfl_up(inc, off, 64);
        if (lane >= off) inc += u;
    }
    if (lane == 63) wsum[w] = inc;
    __syncthreads();
    int wo = 0;
#pragma unroll
    for (int k = 0; k < 16; ++k)
        if (k < w) wo += wsum[k];
    int ex = inc - v + wo;
    if (t < nbuk) { bbase[t] = ex; bcur[t] = ex; }
    if (t == 0) bbase[nbuk] = E;
}

// ---------------- bucket scatter: packed (dlocal<<17 | src) into bucket segments ----
#define SK 16
__global__ __launch_bounds__(256) void k_bscatter(const void* edges, const int* flag,
                                                  int* bcur, int* __restrict__ bucket,
                                                  int E, int nbuk) {
    __shared__ int h[784], sbase[784];
    int t = threadIdx.x;
    for (int i = t; i < 784; i += 256) h[i] = 0;
    __syncthreads();
    int is64 = *flag;
    long long base = (long long)blockIdx.x * 256 * SK;
    int ss[SK], dd[SK], rk[SK];
#pragma unroll
    for (int j = 0; j < SK; ++j) {
        long long i = base + j * 256 + t;
        if (i < E) {
            dd[j] = edge_get(edges, is64, (long long)E + i);
            ss[j] = edge_get(edges, is64, i);
            rk[j] = atomicAdd(&h[dd[j] >> BSH], 1);  // in-block rank
        } else dd[j] = -1;
    }
    __syncthreads();
    for (int i = t; i < nbuk; i += 256)
        if (h[i]) sbase[i] = atomicAdd(&bcur[i], h[i]);
    __syncthreads();
#pragma unroll
    for (int j = 0; j < SK; ++j) {
        if (dd[j] >= 0) {
            int b = dd[j] >> BSH;
            bucket[sbase[b] + rk[j]] = ((dd[j] & (BNODES - 1)) << 17) | ss[j];
        }
    }
}

// ---------------- per-bucket build: row_ptr + dinv + csr (no global atomics) -------
__global__ __launch_bounds__(128) void k_build(const int* __restrict__ bucket,
                                               const int* __restrict__ bbase,
                                               int* __restrict__ row_ptr,
                                               float* __restrict__ dinv,
                                               int* __restrict__ csr,
                                               int N, int nbuk, int E) {
    __shared__ int cnt[128];
    __shared__ int wsum[2];
    int b = blockIdx.x;
    int t = threadIdx.x;
    int nb0 = b << BSH;
    int beg = bbase[b], end = bbase[b + 1];
    cnt[t] = 0;
    __syncthreads();
    for (int e = beg + t; e < end; e += 128)
        atomicAdd(&cnt[bucket[e] >> 17], 1);
    __syncthreads();
    int v = cnt[t];
    int lane = t & 63, w = t >> 6;
    int inc = v;
#pragma unroll
    for (int off = 1; off < 64; off <<= 1) {
        int u = __shfl_up(inc, off, 64);
        if (lane >= off) inc += u;
    }
    if (lane == 63) wsum[w] = inc;
    __syncthreads();
    int excl = inc - v + (w == 1 ? wsum[0] : 0);
    int node = nb0 + t;
    if (node < N) {
        row_ptr[node] = beg + excl;
        dinv[node] = rsqrtf((float)v + 1.0f);
    }
    __syncthreads();
    cnt[t] = beg + excl;  // becomes cursor
    __syncthreads();
    for (int e = beg + t; e < end; e += 128) {
        int p = bucket[e];
        int pos = atomicAdd(&cnt[p >> 17], 1);
        csr[pos] = p & 0x1FFFF;
    }
    if (b == nbuk - 1 && t == 0) row_ptr[N] = E;
}

// ---------------- GEMM1: hs1 = (x @ W1) * dinv[row]  [N,512]x[512,32] ----------------
// M=128 tile; x + W staged via global_load_lds width=16 (no VGPR round-trip).
// xs has no padding (lds-direct needs linear dest) -> bank fix via both-sides swizzle:
// global source column pre-swizzled (kk ^= rr&7 on 16B groups), read XORs it back.
__global__ __launch_bounds__(256) void k_gemm1(const float* __restrict__ x,
                                               const float* __restrict__ W,
                                               const float* __restrict__ dinv,
                                               float* __restrict__ hs1, int N) {
    __shared__ float xs[128][64];
    __shared__ float Ws[64][32];
    int t = threadIdx.x;
    int wv = t >> 6;
    int row0 = blockIdx.x * 128;
    int r0 = t >> 2;           // 0..63
    int c0 = (t & 3) * 8;      // 0,8,16,24
    int swz = (r0 & 7) << 2;   // same for r0 and r0+64

    float acc0[8], acc1[8];
#pragma unroll
    for (int j = 0; j < 8; ++j) { acc0[j] = 0.f; acc1[j] = 0.f; }

    for (int kc = 0; kc < 8; ++kc) {
        // x chunk [128 rows][64 k]: 8 glds16 per thread, swizzled source column
#pragma unroll
        for (int j = 0; j < 8; ++j) {
            int i = t + j * 256;
            int rr = i >> 4, kk = i & 15;
            int grow = row0 + rr;
            if (grow >= N) grow = N - 1;
            const float* gp = x + (size_t)grow * F_IN + kc * 64 + ((kk ^ (rr & 7)) << 2);
            char* lp = (char*)xs + wv * 1024 + j * 4096;  // wave-uniform base
            GLDS16(gp, lp);
        }
        // W chunk [64 k][32 c]: 2 glds16 per thread, linear
#pragma unroll
        for (int j = 0; j < 2; ++j) {
            int i = t + j * 256;
            int kk = i >> 3, cc = i & 7;
            const float* gp = W + (size_t)(kc * 64 + kk) * F_HID + cc * 4;
            char* lp = (char*)Ws + wv * 1024 + j * 4096;
            GLDS16(gp, lp);
        }
        __syncthreads();
#pragma unroll 8
        for (int k = 0; k < 64; ++k) {
            float x0 = xs[r0][k ^ swz];
            float x1 = xs[r0 + 64][k ^ swz];
#pragma unroll
            for (int j = 0; j < 8; ++j) {
                float wvv = Ws[k][c0 + j];
                acc0[j] = fmaf(x0, wvv, acc0[j]);
                acc1[j] = fmaf(x1, wvv, acc1[j]);
            }
        }
        __syncthreads();
    }
    int g0 = row0 + r0, g1 = row0 + r0 + 64;
    if (g0 < N) {
        float di = dinv[g0];
        float* o = hs1 + (size_t)g0 * F_HID + c0;
        *(float4*)(o)     = make_float4(acc0[0] * di, acc0[1] * di, acc0[2] * di, acc0[3] * di);
        *(float4*)(o + 4) = make_float4(acc0[4] * di, acc0[5] * di, acc0[6] * di, acc0[7] * di);
    }
    if (g1 < N) {
        float di = dinv[g1];
        float* o = hs1 + (size_t)g1 * F_HID + c0;
        *(float4*)(o)     = make_float4(acc1[0] * di, acc1[1] * di, acc1[2] * di, acc1[3] * di);
        *(float4*)(o + 4) = make_float4(acc1[4] * di, acc1[5] * di, acc1[6] * di, acc1[7] * di);
    }
}

// ---------------- gather1 + fused gemm2: hs2 = (relu(agg) @ W2) * dinv -------------
// 8 lanes/edge x float4; butterfly leaves the FULL row in all 64 lanes, so gemm2
// runs in-register: lane handles classes {2g,2g+1} over its 4 hidden dims, then
// shfl_xor(1,2,4) reduces over the 8 k-groups. out1 never hits memory.
__global__ __launch_bounds__(256) void k_gather1(const float* __restrict__ hs1,
                                                 const int* __restrict__ csr,
                                                 const int* __restrict__ row_ptr,
                                                 const float* __restrict__ dinv,
                                                 const float* __restrict__ b1,
                                                 const float* __restrict__ W2,
                                                 float* __restrict__ hs2, int N) {
    __shared__ float w2s[32][17];  // pad 17: spreads per-l banks
    int t = threadIdx.x;
    for (int i = t; i < 512; i += 256) w2s[i >> 4][i & 15] = W2[i];
    __syncthreads();
    int node = blockIdx.x * 4 + (t >> 6);
    if (node >= N) return;
    int lane = t & 63;
    int g = lane >> 3, l = lane & 7;      // edge-slot, f4-index
    const float4* h4 = (const float4*)hs1;
    int beg = row_ptr[node], end = row_ptr[node + 1];
    float4 a = make_float4(0.f, 0.f, 0.f, 0.f);
    for (int e = beg + g; e < end; e += 8) {
        int src = csr[e];
        float4 v = h4[(size_t)src * 8 + l];
        a.x += v.x; a.y += v.y; a.z += v.z; a.w += v.w;
    }
    float4 u;
    u = shfl_xor_f4(a, 8);  a.x += u.x; a.y += u.y; a.z += u.z; a.w += u.w;
    u = shfl_xor_f4(a, 16); a.x += u.x; a.y += u.y; a.z += u.z; a.w += u.w;
    u = shfl_xor_f4(a, 32); a.x += u.x; a.y += u.y; a.z += u.z; a.w += u.w;
    // all lanes: relu'd out1 fragment for hidden dims 4l..4l+3
    float4 self = h4[(size_t)node * 8 + l];
    float di = dinv[node];
    float4 bb = ((const float4*)b1)[l];
    float4 r;
    r.x = fmaxf(di * (a.x + self.x) + bb.x, 0.f);
    r.y = fmaxf(di * (a.y + self.y) + bb.y, 0.f);
    r.z = fmaxf(di * (a.z + self.z) + bb.z, 0.f);
    r.w = fmaxf(di * (a.w + self.w) + bb.w, 0.f);
    // gemm2: classes c = 2g, 2g+1 over k = 4l..4l+3
    int k0 = 4 * l, c0 = 2 * g;
    float p0 = r.x * w2s[k0][c0]     + r.y * w2s[k0 + 1][c0]
             + r.z * w2s[k0 + 2][c0] + r.w * w2s[k0 + 3][c0];
    float p1 = r.x * w2s[k0][c0 + 1]     + r.y * w2s[k0 + 1][c0 + 1]
             + r.z * w2s[k0 + 2][c0 + 1] + r.w * w2s[k0 + 3][c0 + 1];
    p0 += __shfl_xor(p0, 1, 64); p1 += __shfl_xor(p1, 1, 64);
    p0 += __shfl_xor(p0, 2, 64); p1 += __shfl_xor(p1, 2, 64);
    p0 += __shfl_xor(p0, 4, 64); p1 += __shfl_xor(p1, 4, 64);
    if (l == 0)
        *(float2*)(hs2 + (size_t)node * N_CLS + c0) = make_float2(p0 * di, p1 * di);
}

// ---------------- gather layer 2: 4 lanes/edge x float4 + log_softmax ---------------
__global__ __launch_bounds__(256) void k_gather2(const float* __restrict__ hs2,
                                                 const int* __restrict__ csr,
                                                 const int* __restrict__ row_ptr,
                                                 const float* __restrict__ dinv,
                                                 const float* __restrict__ b2,
                                                 float* __restrict__ out, int N) {
    int node = blockIdx.x * 4 + (threadIdx.x >> 6);
    if (node >= N) return;
    int lane = threadIdx.x & 63;
    int g = lane >> 2, l = lane & 3;
    const float4* h4 = (const float4*)hs2;
    int beg = row_ptr[node], end = row_ptr[node + 1];
    float4 a = make_float4(0.f, 0.f, 0.f, 0.f);
    for (int e = beg + g; e < end; e += 16) {
        int src = csr[e];
        float4 v = h4[(size_t)src * 4 + l];
        a.x += v.x; a.y += v.y; a.z += v.z; a.w += v.w;
    }
    float4 u;
    u = shfl_xor_f4(a, 4);  a.x += u.x; a.y += u.y; a.z += u.z; a.w += u.w;
    u = shfl_xor_f4(a, 8);  a.x += u.x; a.y += u.y; a.z += u.z; a.w += u.w;
    u = shfl_xor_f4(a, 16); a.x += u.x; a.y += u.y; a.z += u.z; a.w += u.w;
    u = shfl_xor_f4(a, 32); a.x += u.x; a.y += u.y; a.z += u.z; a.w += u.w;
    if (g == 0) {
        float4 self = h4[(size_t)node * 4 + l];
        float di = dinv[node];
        float4 bb = ((const float4*)b2)[l];
        float4 v;
        v.x = di * (a.x + self.x) + bb.x;
        v.y = di * (a.y + self.y) + bb.y;
        v.z = di * (a.z + self.z) + bb.z;
        v.w = di * (a.w + self.w) + bb.w;
        float m = fmaxf(fmaxf(v.x, v.y), fmaxf(v.z, v.w));
        m = fmaxf(m, __shfl_xor(m, 1, 64));
        m = fmaxf(m, __shfl_xor(m, 2, 64));
        float s = __expf(v.x - m) + __expf(v.y - m) + __expf(v.z - m) + __expf(v.w - m);
        s += __shfl_xor(s, 1, 64);
        s += __shfl_xor(s, 2, 64);
        float ls = m + __logf(s);
        float4 r = make_float4(v.x - ls, v.y - ls, v.z - ls, v.w - ls);
        ((float4*)out)[(size_t)node * 4 + l] = r;
    }
}

// ---------------- launch ----------------
extern "C" void kernel_launch(void* const* d_in, const int* in_sizes, int n_in,
                              void* d_out, int out_size, void* d_ws, size_t ws_size,
                              hipStream_t stream) {
    const float* x  = (const float*)d_in[0];
    const void* edges = d_in[1];
    const float* W1 = (const float*)d_in[2];
    const float* b1 = (const float*)d_in[3];
    const float* W2 = (const float*)d_in[4];
    const float* b2 = (const float*)d_in[5];
    float* out = (float*)d_out;

    const int N = in_sizes[0] / F_IN;   // 100000 (packing requires N < 131072)
    const int E = in_sizes[1] / 2;      // 3200000
    const int NBUK = (N + BNODES - 1) >> BSH;  // 782

    char* w = (char*)d_ws;
    size_t off = 0;
    auto take = [&](size_t bytes) {
        size_t o = off;
        off += (bytes + 15) & ~(size_t)15;
        return o;
    };
    float* hs1    = (float*)(w + take((size_t)N * F_HID * 4));
    float* hs2    = (float*)(w + take((size_t)N * N_CLS * 4));
    float* dinv   = (float*)(w + take((size_t)N * 4));
    int* row_ptr  = (int*)(w + take(((size_t)N + 1) * 4));
    int* bucket   = (int*)(w + take((size_t)E * 4));
    int* csr      = (int*)(w + take((size_t)E * 4));
    int* bcnt     = (int*)(w + take(3200));
    int* bbase    = (int*)(w + take(3200));
    int* bcur     = (int*)(w + take(3200));
    int* flag     = (int*)(w + take(16));

    hipLaunchKernelGGL(k_detect, dim3(1), dim3(256), 0, stream, (const int*)edges, flag, bcnt);
    hipLaunchKernelGGL(k_bcount, dim3(512), dim3(256), 0, stream, edges, flag, bcnt, E, NBUK);
    hipLaunchKernelGGL(k_bscan, dim3(1), dim3(1024), 0, stream, bcnt, bbase, bcur, NBUK, E);
    const int SB = (E + 256 * SK - 1) / (256 * SK);
    hipLaunchKernelGGL(k_bscatter, dim3(SB), dim3(256), 0, stream, edges, flag, bcur, bucket, E, NBUK);
    hipLaunchKernelGGL(k_build, dim3(NBUK), dim3(128), 0, stream, bucket, bbase, row_ptr, dinv, csr, N, NBUK, E);
    hipLaunchKernelGGL(k_gemm1, dim3((N + 127) / 128), dim3(256), 0, stream, x, W1, dinv, hs1, N);
    hipLaunchKernelGGL(k_gather1, dim3((N + 3) / 4), dim3(256), 0, stream, hs1, csr, row_ptr, dinv, b1, W2, hs2, N);
    hipLaunchKernelGGL(k_gather2, dim3((N + 3) / 4), dim3(256), 0, stream, hs2, csr, row_ptr, dinv, b2, out, N);
}

// Round 8
// 289.789 us; speedup vs baseline: 1.0272x; 1.0272x over previous
//
#include <hip/hip_runtime.h>
#include <cstdint>
#include <cstddef>

#define F_IN 512
#define F_HID 32
#define N_CLS 16
#define BSH 9                 // 512 nodes per bucket
#define BNODES (1 << BSH)

#define GLDS16(gp, lp) __builtin_amdgcn_global_load_lds( \
    (const __attribute__((address_space(1))) void*)(gp), \
    (__attribute__((address_space(3))) void*)(lp), 16, 0, 0)

__device__ __forceinline__ float4 shfl_xor_f4(float4 v, int mask) {
    v.x = __shfl_xor(v.x, mask, 64);
    v.y = __shfl_xor(v.y, mask, 64);
    v.z = __shfl_xor(v.z, mask, 64);
    v.w = __shfl_xor(v.w, mask, 64);
    return v;
}

// ---------------- edge dtype detection (int32 vs int64) + bcnt zero ----------------
__global__ __launch_bounds__(256) void k_detect(const int* e, int* flag, int* bcnt) {
    __shared__ int zc;
    int t = threadIdx.x;
    if (t == 0) zc = 0;
    __syncthreads();
    int z = 0;
#pragma unroll
    for (int j = 0; j < 4; ++j)
        if (e[2 * (t * 4 + j) + 1] == 0) z++;
    if (z) atomicAdd(&zc, z);
    bcnt[t] = 0;
    __syncthreads();
    if (t == 0) *flag = (zc >= 1016) ? 1 : 0;
}

__device__ __forceinline__ int edge_get(const void* e, int is64, long long idx) {
    return is64 ? (int)((const long long*)e)[idx] : ((const int*)e)[idx];
}

// ---------------- bucket histogram (LDS-aggregated) ----------------
__global__ __launch_bounds__(256) void k_bcount(const void* edges, const int* flag,
                                                int* bcnt, int E, int nbuk) {
    __shared__ int h[256];
    int t = threadIdx.x;
    if (t < nbuk) h[t] = 0;
    __syncthreads();
    int is64 = *flag;
    long long i = (long long)blockIdx.x * blockDim.x + t;
    long long step = (long long)gridDim.x * blockDim.x;
    for (; i < E; i += step) {
        int d = edge_get(edges, is64, (long long)E + i);
        atomicAdd(&h[d >> BSH], 1);
    }
    __syncthreads();
    if (t < nbuk && h[t]) atomicAdd(&bcnt[t], h[t]);
}

// ---------------- bucket base scan (1 block) ----------------
__global__ void k_bscan(const int* bcnt, int* bbase, int* bcur, int nbuk, int E) {
    __shared__ int tmp[256];
    int t = threadIdx.x;
    int v = (t < nbuk) ? bcnt[t] : 0;
    tmp[t] = v;
    __syncthreads();
    for (int off = 1; off < 256; off <<= 1) {
        int a = (t >= off) ? tmp[t - off] : 0;
        __syncthreads();
        tmp[t] += a;
        __syncthreads();
    }
    int ex = tmp[t] - v;
    if (t < nbuk) { bbase[t] = ex; bcur[t] = ex; }
    if (t == 0) bbase[nbuk] = E;
}

// ---------------- bucket scatter: packed (dlocal<<17 | src) into bucket segments ----
#define SK 16
__global__ __launch_bounds__(256) void k_bscatter(const void* edges, const int* flag,
                                                  int* bcur, int* __restrict__ bucket,
                                                  int E, int nbuk) {
    __shared__ int h[256], sbase[256];
    int t = threadIdx.x;
    if (t < nbuk) h[t] = 0;
    __syncthreads();
    int is64 = *flag;
    long long base = (long long)blockIdx.x * 256 * SK;
    int ss[SK], dd[SK], rk[SK];
#pragma unroll
    for (int j = 0; j < SK; ++j) {
        long long i = base + j * 256 + t;
        if (i < E) {
            dd[j] = edge_get(edges, is64, (long long)E + i);
            ss[j] = edge_get(edges, is64, i);
            rk[j] = atomicAdd(&h[dd[j] >> BSH], 1);  // in-block rank
        } else dd[j] = -1;
    }
    __syncthreads();
    if (t < nbuk && h[t]) sbase[t] = atomicAdd(&bcur[t], h[t]);
    __syncthreads();
#pragma unroll
    for (int j = 0; j < SK; ++j) {
        if (dd[j] >= 0) {
            int b = dd[j] >> BSH;
            bucket[sbase[b] + rk[j]] = ((dd[j] & (BNODES - 1)) << 17) | ss[j];
        }
    }
}

// ---------------- per-bucket build: row_ptr + dinv + csr (no global atomics) -------
__global__ __launch_bounds__(512) void k_build(const int* __restrict__ bucket,
                                               const int* __restrict__ bbase,
                                               int* __restrict__ row_ptr,
                                               float* __restrict__ dinv,
                                               int* __restrict__ csr,
                                               int N, int nbuk, int E) {
    __shared__ int cnt[512];
    __shared__ int wsum[8];
    int b = blockIdx.x;
    int t = threadIdx.x;
    int nb0 = b << BSH;
    int beg = bbase[b], end = bbase[b + 1];
    cnt[t] = 0;
    __syncthreads();
    for (int e = beg + t; e < end; e += 512)
        atomicAdd(&cnt[bucket[e] >> 17], 1);
    __syncthreads();
    int v = cnt[t];
    int lane = t & 63, w = t >> 6;
    int inc = v;
#pragma unroll
    for (int off = 1; off < 64; off <<= 1) {
        int u = __shfl_up(inc, off, 64);
        if (lane >= off) inc += u;
    }
    if (lane == 63) wsum[w] = inc;
    __syncthreads();
    int wo = 0;
#pragma unroll
    for (int k = 0; k < 8; ++k)
        if (k < w) wo += wsum[k];
    int excl = inc - v + wo;
    int node = nb0 + t;
    if (node < N) {
        row_ptr[node] = beg + excl;
        dinv[node] = rsqrtf((float)v + 1.0f);
    }
    __syncthreads();
    cnt[t] = beg + excl;  // becomes cursor
    __syncthreads();
    for (int e = beg + t; e < end; e += 512) {
        int p = bucket[e];
        int pos = atomicAdd(&cnt[p >> 17], 1);
        csr[pos] = p & 0x1FFFF;
    }
    if (b == nbuk - 1 && t == 0) row_ptr[N] = E;
}

// ---------------- GEMM1: hs1 = (x @ W1) * dinv[row]  [N,512]x[512,32] ----------------
// 2-phase double-buffered glds16 pipeline (T3-lite): issue chunk kc+1 BEFORE computing
// chunk kc; one barrier/chunk (its vmcnt(0) drain lands after a full compute phase).
// M=64, BK=32; LDS 24 KB -> 6 blocks/CU. Both-sides swizzle on xs (glds dest linear).
__global__ __launch_bounds__(256) void k_gemm1(const float* __restrict__ x,
                                               const float* __restrict__ W,
                                               const float* __restrict__ dinv,
                                               float* __restrict__ hs1, int N) {
    __shared__ float xs[2][64][32];   // 8 KB per buffer
    __shared__ float Ws[2][32][32];   // 4 KB per buffer
    int t = threadIdx.x;
    int wv = t >> 6;
    int row0 = blockIdx.x * 64;
    int r0 = t >> 2;           // 0..63 (one row per thread)
    int c0 = (t & 3) * 8;      // 0,8,16,24
    int sw = r0 & 7;

    float acc[8];
#pragma unroll
    for (int j = 0; j < 8; ++j) acc[j] = 0.f;

    // stage chunk kc into buffer buf
    auto STAGE = [&](int buf, int kc) {
        // x chunk [64 rows][32 k] = 512 f4 groups, 2 per thread; source col swizzled
#pragma unroll
        for (int j = 0; j < 2; ++j) {
            int i = t + j * 256;
            int rr = i >> 3, kk = i & 7;
            int grow = row0 + rr;
            if (grow >= N) grow = N - 1;
            const float* gp = x + (size_t)grow * F_IN + kc * 32 + ((kk ^ (rr & 7)) << 2);
            char* lp = (char*)xs + buf * 8192 + j * 4096 + wv * 1024;  // wave-uniform
            GLDS16(gp, lp);
        }
        // W chunk [32 k][32 c] = 4 KB contiguous
        {
            const float* gp = W + kc * 1024 + t * 4;
            char* lp = (char*)Ws + buf * 4096 + wv * 1024;
            GLDS16(gp, lp);
        }
    };

    STAGE(0, 0);
    __syncthreads();
    int cur = 0;
    for (int kc = 0; kc < 16; ++kc) {
        if (kc < 15) STAGE(cur ^ 1, kc + 1);
        const float* xb = &xs[cur][r0][0];
        const float* wb = &Ws[cur][0][0];
#pragma unroll
        for (int g = 0; g < 8; ++g) {
            int xo = (g ^ sw) << 2;
#pragma unroll
            for (int e = 0; e < 4; ++e) {
                float xv = xb[xo + e];
                const float* wr = wb + (g * 4 + e) * 32 + c0;
#pragma unroll
                for (int j = 0; j < 8; ++j)
                    acc[j] = fmaf(xv, wr[j], acc[j]);
            }
        }
        __syncthreads();
        cur ^= 1;
    }
    int g0 = row0 + r0;
    if (g0 < N) {
        float di = dinv[g0];
        float* o = hs1 + (size_t)g0 * F_HID + c0;
        *(float4*)(o)     = make_float4(acc[0] * di, acc[1] * di, acc[2] * di, acc[3] * di);
        *(float4*)(o + 4) = make_float4(acc[4] * di, acc[5] * di, acc[6] * di, acc[7] * di);
    }
}

// ---------------- gather1 + fused gemm2: hs2 = (relu(agg) @ W2) * dinv -------------
__global__ __launch_bounds__(256) void k_gather1(const float* __restrict__ hs1,
                                                 const int* __restrict__ csr,
                                                 const int* __restrict__ row_ptr,
                                                 const float* __restrict__ dinv,
                                                 const float* __restrict__ b1,
                                                 const float* __restrict__ W2,
                                                 float* __restrict__ hs2, int N) {
    __shared__ float w2s[32][17];
    int t = threadIdx.x;
    for (int i = t; i < 512; i += 256) w2s[i >> 4][i & 15] = W2[i];
    __syncthreads();
    int node = blockIdx.x * 4 + (t >> 6);
    if (node >= N) return;
    int lane = t & 63;
    int g = lane >> 3, l = lane & 7;
    const float4* h4 = (const float4*)hs1;
    int beg = row_ptr[node], end = row_ptr[node + 1];
    float4 a = make_float4(0.f, 0.f, 0.f, 0.f);
    for (int e = beg + g; e < end; e += 8) {
        int src = csr[e];
        float4 v = h4[(size_t)src * 8 + l];
        a.x += v.x; a.y += v.y; a.z += v.z; a.w += v.w;
    }
    float4 u;
    u = shfl_xor_f4(a, 8);  a.x += u.x; a.y += u.y; a.z += u.z; a.w += u.w;
    u = shfl_xor_f4(a, 16); a.x += u.x; a.y += u.y; a.z += u.z; a.w += u.w;
    u = shfl_xor_f4(a, 32); a.x += u.x; a.y += u.y; a.z += u.z; a.w += u.w;
    float4 self = h4[(size_t)node * 8 + l];
    float di = dinv[node];
    float4 bb = ((const float4*)b1)[l];
    float4 r;
    r.x = fmaxf(di * (a.x + self.x) + bb.x, 0.f);
    r.y = fmaxf(di * (a.y + self.y) + bb.y, 0.f);
    r.z = fmaxf(di * (a.z + self.z) + bb.z, 0.f);
    r.w = fmaxf(di * (a.w + self.w) + bb.w, 0.f);
    int k0 = 4 * l, c0 = 2 * g;
    float p0 = r.x * w2s[k0][c0]     + r.y * w2s[k0 + 1][c0]
             + r.z * w2s[k0 + 2][c0] + r.w * w2s[k0 + 3][c0];
    float p1 = r.x * w2s[k0][c0 + 1]     + r.y * w2s[k0 + 1][c0 + 1]
             + r.z * w2s[k0 + 2][c0 + 1] + r.w * w2s[k0 + 3][c0 + 1];
    p0 += __shfl_xor(p0, 1, 64); p1 += __shfl_xor(p1, 1, 64);
    p0 += __shfl_xor(p0, 2, 64); p1 += __shfl_xor(p1, 2, 64);
    p0 += __shfl_xor(p0, 4, 64); p1 += __shfl_xor(p1, 4, 64);
    if (l == 0)
        *(float2*)(hs2 + (size_t)node * N_CLS + c0) = make_float2(p0 * di, p1 * di);
}

// ---------------- gather layer 2: 4 lanes/edge x float4 + log_softmax ---------------
__global__ __launch_bounds__(256) void k_gather2(const float* __restrict__ hs2,
                                                 const int* __restrict__ csr,
                                                 const int* __restrict__ row_ptr,
                                                 const float* __restrict__ dinv,
                                                 const float* __restrict__ b2,
                                                 float* __restrict__ out, int N) {
    int node = blockIdx.x * 4 + (threadIdx.x >> 6);
    if (node >= N) return;
    int lane = threadIdx.x & 63;
    int g = lane >> 2, l = lane & 3;
    const float4* h4 = (const float4*)hs2;
    int beg = row_ptr[node], end = row_ptr[node + 1];
    float4 a = make_float4(0.f, 0.f, 0.f, 0.f);
    for (int e = beg + g; e < end; e += 16) {
        int src = csr[e];
        float4 v = h4[(size_t)src * 4 + l];
        a.x += v.x; a.y += v.y; a.z += v.z; a.w += v.w;
    }
    float4 u;
    u = shfl_xor_f4(a, 4);  a.x += u.x; a.y += u.y; a.z += u.z; a.w += u.w;
    u = shfl_xor_f4(a, 8);  a.x += u.x; a.y += u.y; a.z += u.z; a.w += u.w;
    u = shfl_xor_f4(a, 16); a.x += u.x; a.y += u.y; a.z += u.z; a.w += u.w;
    u = shfl_xor_f4(a, 32); a.x += u.x; a.y += u.y; a.z += u.z; a.w += u.w;
    if (g == 0) {
        float4 self = h4[(size_t)node * 4 + l];
        float di = dinv[node];
        float4 bb = ((const float4*)b2)[l];
        float4 v;
        v.x = di * (a.x + self.x) + bb.x;
        v.y = di * (a.y + self.y) + bb.y;
        v.z = di * (a.z + self.z) + bb.z;
        v.w = di * (a.w + self.w) + bb.w;
        float m = fmaxf(fmaxf(v.x, v.y), fmaxf(v.z, v.w));
        m = fmaxf(m, __shfl_xor(m, 1, 64));
        m = fmaxf(m, __shfl_xor(m, 2, 64));
        float s = __expf(v.x - m) + __expf(v.y - m) + __expf(v.z - m) + __expf(v.w - m);
        s += __shfl_xor(s, 1, 64);
        s += __shfl_xor(s, 2, 64);
        float ls = m + __logf(s);
        float4 r = make_float4(v.x - ls, v.y - ls, v.z - ls, v.w - ls);
        ((float4*)out)[(size_t)node * 4 + l] = r;
    }
}

// ---------------- launch ----------------
extern "C" void kernel_launch(void* const* d_in, const int* in_sizes, int n_in,
                              void* d_out, int out_size, void* d_ws, size_t ws_size,
                              hipStream_t stream) {
    const float* x  = (const float*)d_in[0];
    const void* edges = d_in[1];
    const float* W1 = (const float*)d_in[2];
    const float* b1 = (const float*)d_in[3];
    const float* W2 = (const float*)d_in[4];
    const float* b2 = (const float*)d_in[5];
    float* out = (float*)d_out;

    const int N = in_sizes[0] / F_IN;   // 100000 (packing requires N < 131072)
    const int E = in_sizes[1] / 2;      // 3200000
    const int NBUK = (N + BNODES - 1) >> BSH;  // 196

    char* w = (char*)d_ws;
    size_t off = 0;
    auto take = [&](size_t bytes) {
        size_t o = off;
        off += (bytes + 15) & ~(size_t)15;
        return o;
    };
    float* hs1    = (float*)(w + take((size_t)N * F_HID * 4));
    float* hs2    = (float*)(w + take((size_t)N * N_CLS * 4));
    float* dinv   = (float*)(w + take((size_t)N * 4));
    int* row_ptr  = (int*)(w + take(((size_t)N + 1) * 4));
    int* bucket   = (int*)(w + take((size_t)E * 4));
    int* csr      = (int*)(w + take((size_t)E * 4));
    int* bcnt     = (int*)(w + take(1024));
    int* bbase    = (int*)(w + take(1040));
    int* bcur     = (int*)(w + take(1024));
    int* flag     = (int*)(w + take(16));

    hipLaunchKernelGGL(k_detect, dim3(1), dim3(256), 0, stream, (const int*)edges, flag, bcnt);
    hipLaunchKernelGGL(k_bcount, dim3(512), dim3(256), 0, stream, edges, flag, bcnt, E, NBUK);
    hipLaunchKernelGGL(k_bscan, dim3(1), dim3(256), 0, stream, bcnt, bbase, bcur, NBUK, E);
    const int SB = (E + 256 * SK - 1) / (256 * SK);
    hipLaunchKernelGGL(k_bscatter, dim3(SB), dim3(256), 0, stream, edges, flag, bcur, bucket, E, NBUK);
    hipLaunchKernelGGL(k_build, dim3(NBUK), dim3(512), 0, stream, bucket, bbase, row_ptr, dinv, csr, N, NBUK, E);
    hipLaunchKernelGGL(k_gemm1, dim3((N + 63) / 64), dim3(256), 0, stream, x, W1, dinv, hs1, N);
    hipLaunchKernelGGL(k_gather1, dim3((N + 3) / 4), dim3(256), 0, stream, hs1, csr, row_ptr, dinv, b1, W2, hs2, N);
    hipLaunchKernelGGL(k_gather2, dim3((N + 3) / 4), dim3(256), 0, stream, hs2, csr, row_ptr, dinv, b2, out, N);
}

// Round 9
// 260.650 us; speedup vs baseline: 1.1421x; 1.1118x over previous
//
#include <hip/hip_runtime.h>
#include <cstdint>
#include <cstddef>

#define F_IN 512
#define F_HID 32
#define N_CLS 16
#define BSH 9                 // 512 nodes per bucket
#define BNODES (1 << BSH)
#define CAP 20480             // padded bucket capacity (expected 16327, sigma~128)

#define GLDS16(gp, lp) __builtin_amdgcn_global_load_lds( \
    (const __attribute__((address_space(1))) void*)(gp), \
    (__attribute__((address_space(3))) void*)(lp), 16, 0, 0)

__device__ __forceinline__ float4 shfl_xor_f4(float4 v, int mask) {
    v.x = __shfl_xor(v.x, mask, 64);
    v.y = __shfl_xor(v.y, mask, 64);
    v.z = __shfl_xor(v.z, mask, 64);
    v.w = __shfl_xor(v.w, mask, 64);
    return v;
}

// ------------- edge dtype detection (int32 vs int64) + bucket cursor init ----------
__global__ __launch_bounds__(256) void k_detect(const int* e, int* flag, int* bcur,
                                                int nbuk) {
    __shared__ int zc;
    int t = threadIdx.x;
    if (t == 0) zc = 0;
    __syncthreads();
    int z = 0;
#pragma unroll
    for (int j = 0; j < 4; ++j)
        if (e[2 * (t * 4 + j) + 1] == 0) z++;
    if (z) atomicAdd(&zc, z);
    for (int i = t; i < nbuk; i += 256) bcur[i] = i * CAP;
    __syncthreads();
    if (t == 0) *flag = (zc >= 1016) ? 1 : 0;
}

__device__ __forceinline__ int edge_get(const void* e, int is64, long long idx) {
    return is64 ? (int)((const long long*)e)[idx] : ((const int*)e)[idx];
}

// ---------------- bucket scatter: packed (dlocal<<17 | src) into padded buckets ----
#define SK 16
__global__ __launch_bounds__(256) void k_bscatter(const void* edges, const int* flag,
                                                  int* bcur, int* __restrict__ bucket,
                                                  int E, int nbuk) {
    __shared__ int h[256], sbase[256];
    int t = threadIdx.x;
    if (t < nbuk) h[t] = 0;
    __syncthreads();
    int is64 = *flag;
    long long base = (long long)blockIdx.x * 256 * SK;
    int ss[SK], dd[SK], rk[SK];
#pragma unroll
    for (int j = 0; j < SK; ++j) {
        long long i = base + j * 256 + t;
        if (i < E) {
            dd[j] = edge_get(edges, is64, (long long)E + i);
            ss[j] = edge_get(edges, is64, i);
            rk[j] = atomicAdd(&h[dd[j] >> BSH], 1);  // in-block rank
        } else dd[j] = -1;
    }
    __syncthreads();
    if (t < nbuk && h[t]) sbase[t] = atomicAdd(&bcur[t], h[t]);
    __syncthreads();
#pragma unroll
    for (int j = 0; j < SK; ++j) {
        if (dd[j] >= 0) {
            int b = dd[j] >> BSH;
            int pos = sbase[b] + rk[j];
            if (pos < (b + 1) * CAP)  // overflow guard (statistically unreachable)
                bucket[pos] = ((dd[j] & (BNODES - 1)) << 17) | ss[j];
        }
    }
}

// ------- per-bucket build: rbeg/rend + dinv + csr (no global scan, no atomics) -----
__global__ __launch_bounds__(512) void k_build(const int* __restrict__ bucket,
                                               const int* __restrict__ bcur,
                                               int* __restrict__ rbeg,
                                               int* __restrict__ rend,
                                               float* __restrict__ dinv,
                                               int* __restrict__ csr, int N) {
    __shared__ int cnt[512];
    __shared__ int wsum[8];
    int b = blockIdx.x;
    int t = threadIdx.x;
    int nb0 = b << BSH;
    int beg = b * CAP, end = bcur[b];
    cnt[t] = 0;
    __syncthreads();
    for (int e = beg + t; e < end; e += 512)
        atomicAdd(&cnt[bucket[e] >> 17], 1);
    __syncthreads();
    int v = cnt[t];
    int lane = t & 63, w = t >> 6;
    int inc = v;
#pragma unroll
    for (int off = 1; off < 64; off <<= 1) {
        int u = __shfl_up(inc, off, 64);
        if (lane >= off) inc += u;
    }
    if (lane == 63) wsum[w] = inc;
    __syncthreads();
    int wo = 0;
#pragma unroll
    for (int k = 0; k < 8; ++k)
        if (k < w) wo += wsum[k];
    int excl = inc - v + wo;
    int node = nb0 + t;
    if (node < N) {
        rbeg[node] = beg + excl;
        rend[node] = beg + excl + v;
        dinv[node] = rsqrtf((float)v + 1.0f);
    }
    __syncthreads();
    cnt[t] = beg + excl;  // becomes cursor
    __syncthreads();
    for (int e = beg + t; e < end; e += 512) {
        int p = bucket[e];
        int pos = atomicAdd(&cnt[p >> 17], 1);
        csr[pos] = p & 0x1FFFF;
    }
}

// ---------------- GEMM1: hs1 = (x @ W1) * dinv[row]  [N,512]x[512,32] ----------------
// 2-phase double-buffered glds16 pipeline; M=64, BK=32; LDS 24 KB -> 6 blocks/CU.
__global__ __launch_bounds__(256) void k_gemm1(const float* __restrict__ x,
                                               const float* __restrict__ W,
                                               const float* __restrict__ dinv,
                                               float* __restrict__ hs1, int N) {
    __shared__ float xs[2][64][32];   // 8 KB per buffer
    __shared__ float Ws[2][32][32];   // 4 KB per buffer
    int t = threadIdx.x;
    int wv = t >> 6;
    int row0 = blockIdx.x * 64;
    int r0 = t >> 2;           // 0..63 (one row per thread)
    int c0 = (t & 3) * 8;      // 0,8,16,24
    int sw = r0 & 7;

    float acc[8];
#pragma unroll
    for (int j = 0; j < 8; ++j) acc[j] = 0.f;

    auto STAGE = [&](int buf, int kc) {
#pragma unroll
        for (int j = 0; j < 2; ++j) {
            int i = t + j * 256;
            int rr = i >> 3, kk = i & 7;
            int grow = row0 + rr;
            if (grow >= N) grow = N - 1;
            const float* gp = x + (size_t)grow * F_IN + kc * 32 + ((kk ^ (rr & 7)) << 2);
            char* lp = (char*)xs + buf * 8192 + j * 4096 + wv * 1024;  // wave-uniform
            GLDS16(gp, lp);
        }
        {
            const float* gp = W + kc * 1024 + t * 4;
            char* lp = (char*)Ws + buf * 4096 + wv * 1024;
            GLDS16(gp, lp);
        }
    };

    STAGE(0, 0);
    __syncthreads();
    int cur = 0;
    for (int kc = 0; kc < 16; ++kc) {
        if (kc < 15) STAGE(cur ^ 1, kc + 1);
        const float* xb = &xs[cur][r0][0];
        const float* wb = &Ws[cur][0][0];
#pragma unroll
        for (int g = 0; g < 8; ++g) {
            int xo = (g ^ sw) << 2;
#pragma unroll
            for (int e = 0; e < 4; ++e) {
                float xv = xb[xo + e];
                const float* wr = wb + (g * 4 + e) * 32 + c0;
#pragma unroll
                for (int j = 0; j < 8; ++j)
                    acc[j] = fmaf(xv, wr[j], acc[j]);
            }
        }
        __syncthreads();
        cur ^= 1;
    }
    int g0 = row0 + r0;
    if (g0 < N) {
        float di = dinv[g0];
        float* o = hs1 + (size_t)g0 * F_HID + c0;
        *(float4*)(o)     = make_float4(acc[0] * di, acc[1] * di, acc[2] * di, acc[3] * di);
        *(float4*)(o + 4) = make_float4(acc[4] * di, acc[5] * di, acc[6] * di, acc[7] * di);
    }
}

// ---------------- gather1 + fused gemm2: hs2 = (relu(agg) @ W2) * dinv -------------
__global__ __launch_bounds__(256) void k_gather1(const float* __restrict__ hs1,
                                                 const int* __restrict__ csr,
                                                 const int* __restrict__ rbeg,
                                                 const int* __restrict__ rend,
                                                 const float* __restrict__ dinv,
                                                 const float* __restrict__ b1,
                                                 const float* __restrict__ W2,
                                                 float* __restrict__ hs2, int N) {
    __shared__ float w2s[32][17];
    int t = threadIdx.x;
    for (int i = t; i < 512; i += 256) w2s[i >> 4][i & 15] = W2[i];
    __syncthreads();
    int node = blockIdx.x * 4 + (t >> 6);
    if (node >= N) return;
    int lane = t & 63;
    int g = lane >> 3, l = lane & 7;
    const float4* h4 = (const float4*)hs1;
    int beg = rbeg[node], end = rend[node];
    float4 a = make_float4(0.f, 0.f, 0.f, 0.f);
    for (int e = beg + g; e < end; e += 8) {
        int src = csr[e];
        float4 v = h4[(size_t)src * 8 + l];
        a.x += v.x; a.y += v.y; a.z += v.z; a.w += v.w;
    }
    float4 u;
    u = shfl_xor_f4(a, 8);  a.x += u.x; a.y += u.y; a.z += u.z; a.w += u.w;
    u = shfl_xor_f4(a, 16); a.x += u.x; a.y += u.y; a.z += u.z; a.w += u.w;
    u = shfl_xor_f4(a, 32); a.x += u.x; a.y += u.y; a.z += u.z; a.w += u.w;
    float4 self = h4[(size_t)node * 8 + l];
    float di = dinv[node];
    float4 bb = ((const float4*)b1)[l];
    float4 r;
    r.x = fmaxf(di * (a.x + self.x) + bb.x, 0.f);
    r.y = fmaxf(di * (a.y + self.y) + bb.y, 0.f);
    r.z = fmaxf(di * (a.z + self.z) + bb.z, 0.f);
    r.w = fmaxf(di * (a.w + self.w) + bb.w, 0.f);
    int k0 = 4 * l, c0 = 2 * g;
    float p0 = r.x * w2s[k0][c0]     + r.y * w2s[k0 + 1][c0]
             + r.z * w2s[k0 + 2][c0] + r.w * w2s[k0 + 3][c0];
    float p1 = r.x * w2s[k0][c0 + 1]     + r.y * w2s[k0 + 1][c0 + 1]
             + r.z * w2s[k0 + 2][c0 + 1] + r.w * w2s[k0 + 3][c0 + 1];
    p0 += __shfl_xor(p0, 1, 64); p1 += __shfl_xor(p1, 1, 64);
    p0 += __shfl_xor(p0, 2, 64); p1 += __shfl_xor(p1, 2, 64);
    p0 += __shfl_xor(p0, 4, 64); p1 += __shfl_xor(p1, 4, 64);
    if (l == 0)
        *(float2*)(hs2 + (size_t)node * N_CLS + c0) = make_float2(p0 * di, p1 * di);
}

// ---------------- gather layer 2: 4 lanes/edge x float4 + log_softmax ---------------
__global__ __launch_bounds__(256) void k_gather2(const float* __restrict__ hs2,
                                                 const int* __restrict__ csr,
                                                 const int* __restrict__ rbeg,
                                                 const int* __restrict__ rend,
                                                 const float* __restrict__ dinv,
                                                 const float* __restrict__ b2,
                                                 float* __restrict__ out, int N) {
    int node = blockIdx.x * 4 + (threadIdx.x >> 6);
    if (node >= N) return;
    int lane = threadIdx.x & 63;
    int g = lane >> 2, l = lane & 3;
    const float4* h4 = (const float4*)hs2;
    int beg = rbeg[node], end = rend[node];
    float4 a = make_float4(0.f, 0.f, 0.f, 0.f);
    for (int e = beg + g; e < end; e += 16) {
        int src = csr[e];
        float4 v = h4[(size_t)src * 4 + l];
        a.x += v.x; a.y += v.y; a.z += v.z; a.w += v.w;
    }
    float4 u;
    u = shfl_xor_f4(a, 4);  a.x += u.x; a.y += u.y; a.z += u.z; a.w += u.w;
    u = shfl_xor_f4(a, 8);  a.x += u.x; a.y += u.y; a.z += u.z; a.w += u.w;
    u = shfl_xor_f4(a, 16); a.x += u.x; a.y += u.y; a.z += u.z; a.w += u.w;
    u = shfl_xor_f4(a, 32); a.x += u.x; a.y += u.y; a.z += u.z; a.w += u.w;
    if (g == 0) {
        float4 self = h4[(size_t)node * 4 + l];
        float di = dinv[node];
        float4 bb = ((const float4*)b2)[l];
        float4 v;
        v.x = di * (a.x + self.x) + bb.x;
        v.y = di * (a.y + self.y) + bb.y;
        v.z = di * (a.z + self.z) + bb.z;
        v.w = di * (a.w + self.w) + bb.w;
        float m = fmaxf(fmaxf(v.x, v.y), fmaxf(v.z, v.w));
        m = fmaxf(m, __shfl_xor(m, 1, 64));
        m = fmaxf(m, __shfl_xor(m, 2, 64));
        float s = __expf(v.x - m) + __expf(v.y - m) + __expf(v.z - m) + __expf(v.w - m);
        s += __shfl_xor(s, 1, 64);
        s += __shfl_xor(s, 2, 64);
        float ls = m + __logf(s);
        float4 r = make_float4(v.x - ls, v.y - ls, v.z - ls, v.w - ls);
        ((float4*)out)[(size_t)node * 4 + l] = r;
    }
}

// ---------------- launch ----------------
extern "C" void kernel_launch(void* const* d_in, const int* in_sizes, int n_in,
                              void* d_out, int out_size, void* d_ws, size_t ws_size,
                              hipStream_t stream) {
    const float* x  = (const float*)d_in[0];
    const void* edges = d_in[1];
    const float* W1 = (const float*)d_in[2];
    const float* b1 = (const float*)d_in[3];
    const float* W2 = (const float*)d_in[4];
    const float* b2 = (const float*)d_in[5];
    float* out = (float*)d_out;

    const int N = in_sizes[0] / F_IN;   // 100000 (packing requires N < 131072)
    const int E = in_sizes[1] / 2;      // 3200000
    const int NBUK = (N + BNODES - 1) >> BSH;  // 196

    char* w = (char*)d_ws;
    size_t off = 0;
    auto take = [&](size_t bytes) {
        size_t o = off;
        off += (bytes + 15) & ~(size_t)15;
        return o;
    };
    float* hs1    = (float*)(w + take((size_t)N * F_HID * 4));
    float* hs2    = (float*)(w + take((size_t)N * N_CLS * 4));
    float* dinv   = (float*)(w + take((size_t)N * 4));
    int* rbeg     = (int*)(w + take((size_t)N * 4));
    int* rend     = (int*)(w + take((size_t)N * 4));
    int* bucket   = (int*)(w + take((size_t)NBUK * CAP * 4));
    int* csr      = (int*)(w + take((size_t)NBUK * CAP * 4));
    int* bcur     = (int*)(w + take(1024));
    int* flag     = (int*)(w + take(16));

    hipLaunchKernelGGL(k_detect, dim3(1), dim3(256), 0, stream, (const int*)edges, flag, bcur, NBUK);
    const int SB = (E + 256 * SK - 1) / (256 * SK);
    hipLaunchKernelGGL(k_bscatter, dim3(SB), dim3(256), 0, stream, edges, flag, bcur, bucket, E, NBUK);
    hipLaunchKernelGGL(k_build, dim3(NBUK), dim3(512), 0, stream, bucket, bcur, rbeg, rend, dinv, csr, N);
    hipLaunchKernelGGL(k_gemm1, dim3((N + 63) / 64), dim3(256), 0, stream, x, W1, dinv, hs1, N);
    hipLaunchKernelGGL(k_gather1, dim3((N + 3) / 4), dim3(256), 0, stream, hs1, csr, rbeg, rend, dinv, b1, W2, hs2, N);
    hipLaunchKernelGGL(k_gather2, dim3((N + 3) / 4), dim3(256), 0, stream, hs2, csr, rbeg, rend, dinv, b2, out, N);
}

// Round 10
// 251.996 us; speedup vs baseline: 1.1813x; 1.0343x over previous
//
#include <hip/hip_runtime.h>
#include <cstdint>
#include <cstddef>

#define F_IN 512
#define F_HID 32
#define N_CLS 16
#define BSH 9                 // 512 nodes per bucket
#define BNODES (1 << BSH)
#define CAP 20480             // padded bucket capacity (expected 16327, sigma~128)

#define GLDS16(gp, lp) __builtin_amdgcn_global_load_lds( \
    (const __attribute__((address_space(1))) void*)(gp), \
    (__attribute__((address_space(3))) void*)(lp), 16, 0, 0)

__device__ __forceinline__ float4 shfl_xor_f4(float4 v, int mask) {
    v.x = __shfl_xor(v.x, mask, 64);
    v.y = __shfl_xor(v.y, mask, 64);
    v.z = __shfl_xor(v.z, mask, 64);
    v.w = __shfl_xor(v.w, mask, 64);
    return v;
}

// ------------- edge dtype detection (int32 vs int64) + bucket cursor init ----------
__global__ __launch_bounds__(256) void k_detect(const int* e, int* flag, int* bcur,
                                                int nbuk) {
    __shared__ int zc;
    int t = threadIdx.x;
    if (t == 0) zc = 0;
    __syncthreads();
    int z = 0;
#pragma unroll
    for (int j = 0; j < 4; ++j)
        if (e[2 * (t * 4 + j) + 1] == 0) z++;
    if (z) atomicAdd(&zc, z);
    for (int i = t; i < nbuk; i += 256) bcur[i] = i * CAP;
    __syncthreads();
    if (t == 0) *flag = (zc >= 1016) ? 1 : 0;
}

__device__ __forceinline__ int edge_get(const void* e, int is64, long long idx) {
    return is64 ? (int)((const long long*)e)[idx] : ((const int*)e)[idx];
}

// ---------------- bucket scatter: packed (dlocal<<17 | src) into padded buckets ----
#define SK 16
__global__ __launch_bounds__(256) void k_bscatter(const void* edges, const int* flag,
                                                  int* bcur, int* __restrict__ bucket,
                                                  int E, int nbuk) {
    __shared__ int h[256], sbase[256];
    int t = threadIdx.x;
    if (t < nbuk) h[t] = 0;
    __syncthreads();
    int is64 = *flag;
    long long base = (long long)blockIdx.x * 256 * SK;
    int ss[SK], dd[SK], rk[SK];
#pragma unroll
    for (int j = 0; j < SK; ++j) {
        long long i = base + j * 256 + t;
        if (i < E) {
            dd[j] = edge_get(edges, is64, (long long)E + i);
            ss[j] = edge_get(edges, is64, i);
            rk[j] = atomicAdd(&h[dd[j] >> BSH], 1);  // in-block rank
        } else dd[j] = -1;
    }
    __syncthreads();
    if (t < nbuk && h[t]) sbase[t] = atomicAdd(&bcur[t], h[t]);
    __syncthreads();
#pragma unroll
    for (int j = 0; j < SK; ++j) {
        if (dd[j] >= 0) {
            int b = dd[j] >> BSH;
            int pos = sbase[b] + rk[j];
            if (pos < (b + 1) * CAP)  // overflow guard (statistically unreachable)
                bucket[pos] = ((dd[j] & (BNODES - 1)) << 17) | ss[j];
        }
    }
}

// ------- per-bucket build: rbeg/rend + dinv + csr (no global scan, no atomics) -----
__global__ __launch_bounds__(512) void k_build(const int* __restrict__ bucket,
                                               const int* __restrict__ bcur,
                                               int* __restrict__ rbeg,
                                               int* __restrict__ rend,
                                               float* __restrict__ dinv,
                                               int* __restrict__ csr, int N) {
    __shared__ int cnt[512];
    __shared__ int wsum[8];
    int b = blockIdx.x;
    int t = threadIdx.x;
    int nb0 = b << BSH;
    int beg = b * CAP, end = bcur[b];
    cnt[t] = 0;
    __syncthreads();
    for (int e = beg + t; e < end; e += 512)
        atomicAdd(&cnt[bucket[e] >> 17], 1);
    __syncthreads();
    int v = cnt[t];
    int lane = t & 63, w = t >> 6;
    int inc = v;
#pragma unroll
    for (int off = 1; off < 64; off <<= 1) {
        int u = __shfl_up(inc, off, 64);
        if (lane >= off) inc += u;
    }
    if (lane == 63) wsum[w] = inc;
    __syncthreads();
    int wo = 0;
#pragma unroll
    for (int k = 0; k < 8; ++k)
        if (k < w) wo += wsum[k];
    int excl = inc - v + wo;
    int node = nb0 + t;
    if (node < N) {
        rbeg[node] = beg + excl;
        rend[node] = beg + excl + v;
        dinv[node] = rsqrtf((float)v + 1.0f);
    }
    __syncthreads();
    cnt[t] = beg + excl;  // becomes cursor
    __syncthreads();
    for (int e = beg + t; e < end; e += 512) {
        int p = bucket[e];
        int pos = atomicAdd(&cnt[p >> 17], 1);
        csr[pos] = p & 0x1FFFF;
    }
}

// ---------------- GEMM1: hs1 = (x @ W1) * dinv[row]  [N,512]x[512,32] ----------------
// M=128 tile, 2 rows (r0, r0+64) x 8 cols per thread; 2-phase double-buffered glds16
// pipeline, BK=32. LDS 40 KB -> 4 blocks/CU. Both-sides swizzle on xs.
__global__ __launch_bounds__(256) void k_gemm1(const float* __restrict__ x,
                                               const float* __restrict__ W,
                                               const float* __restrict__ dinv,
                                               float* __restrict__ hs1, int N) {
    __shared__ float xs[2][128][32];  // 16 KB per buffer
    __shared__ float Ws[2][32][32];   // 4 KB per buffer
    int t = threadIdx.x;
    int wv = t >> 6;
    int row0 = blockIdx.x * 128;
    int r0 = t >> 2;           // 0..63
    int c0 = (t & 3) * 8;      // 0,8,16,24
    int sw = r0 & 7;           // same for r0 and r0+64

    float acc0[8], acc1[8];
#pragma unroll
    for (int j = 0; j < 8; ++j) { acc0[j] = 0.f; acc1[j] = 0.f; }

    auto STAGE = [&](int buf, int kc) {
        // x chunk [128 rows][32 k] = 1024 f4, 4 per thread; source col swizzled
#pragma unroll
        for (int j = 0; j < 4; ++j) {
            int i = t + j * 256;
            int rr = i >> 3, kk = i & 7;
            int grow = row0 + rr;
            if (grow >= N) grow = N - 1;
            const float* gp = x + (size_t)grow * F_IN + kc * 32 + ((kk ^ (rr & 7)) << 2);
            char* lp = (char*)xs + buf * 16384 + j * 4096 + wv * 1024;  // wave-uniform
            GLDS16(gp, lp);
        }
        // W chunk [32 k][32 c] = 4 KB contiguous
        {
            const float* gp = W + kc * 1024 + t * 4;
            char* lp = (char*)Ws + buf * 4096 + wv * 1024;
            GLDS16(gp, lp);
        }
    };

    STAGE(0, 0);
    __syncthreads();
    int cur = 0;
    for (int kc = 0; kc < 16; ++kc) {
        if (kc < 15) STAGE(cur ^ 1, kc + 1);
        const float* xb0 = &xs[cur][r0][0];
        const float* xb1 = &xs[cur][r0 + 64][0];
        const float* wb = &Ws[cur][0][0];
#pragma unroll
        for (int g = 0; g < 8; ++g) {
            int xo = (g ^ sw) << 2;
#pragma unroll
            for (int e = 0; e < 4; ++e) {
                float x0 = xb0[xo + e];
                float x1 = xb1[xo + e];
                const float* wr = wb + (g * 4 + e) * 32 + c0;
#pragma unroll
                for (int j = 0; j < 8; ++j) {
                    float wvv = wr[j];
                    acc0[j] = fmaf(x0, wvv, acc0[j]);
                    acc1[j] = fmaf(x1, wvv, acc1[j]);
                }
            }
        }
        __syncthreads();
        cur ^= 1;
    }
    int g0 = row0 + r0, g1 = row0 + r0 + 64;
    if (g0 < N) {
        float di = dinv[g0];
        float* o = hs1 + (size_t)g0 * F_HID + c0;
        *(float4*)(o)     = make_float4(acc0[0] * di, acc0[1] * di, acc0[2] * di, acc0[3] * di);
        *(float4*)(o + 4) = make_float4(acc0[4] * di, acc0[5] * di, acc0[6] * di, acc0[7] * di);
    }
    if (g1 < N) {
        float di = dinv[g1];
        float* o = hs1 + (size_t)g1 * F_HID + c0;
        *(float4*)(o)     = make_float4(acc1[0] * di, acc1[1] * di, acc1[2] * di, acc1[3] * di);
        *(float4*)(o + 4) = make_float4(acc1[4] * di, acc1[5] * di, acc1[6] * di, acc1[7] * di);
    }
}

// ---------------- gather1 + fused gemm2: hs2 = (relu(agg) @ W2) * dinv -------------
__global__ __launch_bounds__(256) void k_gather1(const float* __restrict__ hs1,
                                                 const int* __restrict__ csr,
                                                 const int* __restrict__ rbeg,
                                                 const int* __restrict__ rend,
                                                 const float* __restrict__ dinv,
                                                 const float* __restrict__ b1,
                                                 const float* __restrict__ W2,
                                                 float* __restrict__ hs2, int N) {
    __shared__ float w2s[32][17];
    int t = threadIdx.x;
    for (int i = t; i < 512; i += 256) w2s[i >> 4][i & 15] = W2[i];
    __syncthreads();
    int node = blockIdx.x * 4 + (t >> 6);
    if (node >= N) return;
    int lane = t & 63;
    int g = lane >> 3, l = lane & 7;
    const float4* h4 = (const float4*)hs1;
    int beg = rbeg[node], end = rend[node];
    float4 a = make_float4(0.f, 0.f, 0.f, 0.f);
    for (int e = beg + g; e < end; e += 8) {
        int src = csr[e];
        float4 v = h4[(size_t)src * 8 + l];
        a.x += v.x; a.y += v.y; a.z += v.z; a.w += v.w;
    }
    float4 u;
    u = shfl_xor_f4(a, 8);  a.x += u.x; a.y += u.y; a.z += u.z; a.w += u.w;
    u = shfl_xor_f4(a, 16); a.x += u.x; a.y += u.y; a.z += u.z; a.w += u.w;
    u = shfl_xor_f4(a, 32); a.x += u.x; a.y += u.y; a.z += u.z; a.w += u.w;
    float4 self = h4[(size_t)node * 8 + l];
    float di = dinv[node];
    float4 bb = ((const float4*)b1)[l];
    float4 r;
    r.x = fmaxf(di * (a.x + self.x) + bb.x, 0.f);
    r.y = fmaxf(di * (a.y + self.y) + bb.y, 0.f);
    r.z = fmaxf(di * (a.z + self.z) + bb.z, 0.f);
    r.w = fmaxf(di * (a.w + self.w) + bb.w, 0.f);
    int k0 = 4 * l, c0 = 2 * g;
    float p0 = r.x * w2s[k0][c0]     + r.y * w2s[k0 + 1][c0]
             + r.z * w2s[k0 + 2][c0] + r.w * w2s[k0 + 3][c0];
    float p1 = r.x * w2s[k0][c0 + 1]     + r.y * w2s[k0 + 1][c0 + 1]
             + r.z * w2s[k0 + 2][c0 + 1] + r.w * w2s[k0 + 3][c0 + 1];
    p0 += __shfl_xor(p0, 1, 64); p1 += __shfl_xor(p1, 1, 64);
    p0 += __shfl_xor(p0, 2, 64); p1 += __shfl_xor(p1, 2, 64);
    p0 += __shfl_xor(p0, 4, 64); p1 += __shfl_xor(p1, 4, 64);
    if (l == 0)
        *(float2*)(hs2 + (size_t)node * N_CLS + c0) = make_float2(p0 * di, p1 * di);
}

// ---------------- gather layer 2: 4 lanes/edge x float4 + log_softmax ---------------
__global__ __launch_bounds__(256) void k_gather2(const float* __restrict__ hs2,
                                                 const int* __restrict__ csr,
                                                 const int* __restrict__ rbeg,
                                                 const int* __restrict__ rend,
                                                 const float* __restrict__ dinv,
                                                 const float* __restrict__ b2,
                                                 float* __restrict__ out, int N) {
    int node = blockIdx.x * 4 + (threadIdx.x >> 6);
    if (node >= N) return;
    int lane = threadIdx.x & 63;
    int g = lane >> 2, l = lane & 3;
    const float4* h4 = (const float4*)hs2;
    int beg = rbeg[node], end = rend[node];
    float4 a = make_float4(0.f, 0.f, 0.f, 0.f);
    for (int e = beg + g; e < end; e += 16) {
        int src = csr[e];
        float4 v = h4[(size_t)src * 4 + l];
        a.x += v.x; a.y += v.y; a.z += v.z; a.w += v.w;
    }
    float4 u;
    u = shfl_xor_f4(a, 4);  a.x += u.x; a.y += u.y; a.z += u.z; a.w += u.w;
    u = shfl_xor_f4(a, 8);  a.x += u.x; a.y += u.y; a.z += u.z; a.w += u.w;
    u = shfl_xor_f4(a, 16); a.x += u.x; a.y += u.y; a.z += u.z; a.w += u.w;
    u = shfl_xor_f4(a, 32); a.x += u.x; a.y += u.y; a.z += u.z; a.w += u.w;
    if (g == 0) {
        float4 self = h4[(size_t)node * 4 + l];
        float di = dinv[node];
        float4 bb = ((const float4*)b2)[l];
        float4 v;
        v.x = di * (a.x + self.x) + bb.x;
        v.y = di * (a.y + self.y) + bb.y;
        v.z = di * (a.z + self.z) + bb.z;
        v.w = di * (a.w + self.w) + bb.w;
        float m = fmaxf(fmaxf(v.x, v.y), fmaxf(v.z, v.w));
        m = fmaxf(m, __shfl_xor(m, 1, 64));
        m = fmaxf(m, __shfl_xor(m, 2, 64));
        float s = __expf(v.x - m) + __expf(v.y - m) + __expf(v.z - m) + __expf(v.w - m);
        s += __shfl_xor(s, 1, 64);
        s += __shfl_xor(s, 2, 64);
        float ls = m + __logf(s);
        float4 r = make_float4(v.x - ls, v.y - ls, v.z - ls, v.w - ls);
        ((float4*)out)[(size_t)node * 4 + l] = r;
    }
}

// ---------------- launch ----------------
extern "C" void kernel_launch(void* const* d_in, const int* in_sizes, int n_in,
                              void* d_out, int out_size, void* d_ws, size_t ws_size,
                              hipStream_t stream) {
    const float* x  = (const float*)d_in[0];
    const void* edges = d_in[1];
    const float* W1 = (const float*)d_in[2];
    const float* b1 = (const float*)d_in[3];
    const float* W2 = (const float*)d_in[4];
    const float* b2 = (const float*)d_in[5];
    float* out = (float*)d_out;

    const int N = in_sizes[0] / F_IN;   // 100000 (packing requires N < 131072)
    const int E = in_sizes[1] / 2;      // 3200000
    const int NBUK = (N + BNODES - 1) >> BSH;  // 196

    char* w = (char*)d_ws;
    size_t off = 0;
    auto take = [&](size_t bytes) {
        size_t o = off;
        off += (bytes + 15) & ~(size_t)15;
        return o;
    };
    float* hs1    = (float*)(w + take((size_t)N * F_HID * 4));
    float* hs2    = (float*)(w + take((size_t)N * N_CLS * 4));
    float* dinv   = (float*)(w + take((size_t)N * 4));
    int* rbeg     = (int*)(w + take((size_t)N * 4));
    int* rend     = (int*)(w + take((size_t)N * 4));
    int* bucket   = (int*)(w + take((size_t)NBUK * CAP * 4));
    int* csr      = (int*)(w + take((size_t)NBUK * CAP * 4));
    int* bcur     = (int*)(w + take(1024));
    int* flag     = (int*)(w + take(16));

    hipLaunchKernelGGL(k_detect, dim3(1), dim3(256), 0, stream, (const int*)edges, flag, bcur, NBUK);
    const int SB = (E + 256 * SK - 1) / (256 * SK);
    hipLaunchKernelGGL(k_bscatter, dim3(SB), dim3(256), 0, stream, edges, flag, bcur, bucket, E, NBUK);
    hipLaunchKernelGGL(k_build, dim3(NBUK), dim3(512), 0, stream, bucket, bcur, rbeg, rend, dinv, csr, N);
    hipLaunchKernelGGL(k_gemm1, dim3((N + 127) / 128), dim3(256), 0, stream, x, W1, dinv, hs1, N);
    hipLaunchKernelGGL(k_gather1, dim3((N + 3) / 4), dim3(256), 0, stream, hs1, csr, rbeg, rend, dinv, b1, W2, hs2, N);
    hipLaunchKernelGGL(k_gather2, dim3((N + 3) / 4), dim3(256), 0, stream, hs2, csr, rbeg, rend, dinv, b2, out, N);
}